// Round 19
// baseline (126.643 us; speedup 1.0000x reference)
//
#include <hip/hip_runtime.h>
#include <hip/hip_bf16.h>

#define BATCH 64
#define SEQT  512
#define EMB   1024
#define HID   2048
#define VOC   32000
#define KSPLIT 4

using bf16x8 = __attribute__((ext_vector_type(8))) __bf16;
using f32x4  = __attribute__((ext_vector_type(4))) float;

__device__ __forceinline__ void split2(float x, __bf16& hi, __bf16& lo) {
  hi = (__bf16)x;
  lo = (__bf16)(x - (float)hi);
}

// ---------------------------------------------------------------------------
// Layer kernel (round-9 verbatim, passing): h_out = tanh(A @ W + bias),
// split-bf16 (3 MFMA products), 16x16x32 MFMA, 256 blocks x 16 waves,
// LDS reduce.
// ---------------------------------------------------------------------------
template <int KTOT, bool GATHER>
__global__ __launch_bounds__(1024) void layer_kernel(
    const int* __restrict__ X, const float* __restrict__ emb,
    const __hip_bfloat16* __restrict__ hin_hi,
    const __hip_bfloat16* __restrict__ hin_lo,
    const float* __restrict__ W, const float* __restrict__ bias,
    __hip_bfloat16* __restrict__ hout_hi,
    __hip_bfloat16* __restrict__ hout_lo) {
  constexpr int KCHUNK = KTOT / 16;   // 128 (HID) / 64 (EMB)
  constexpr int KSTEPS = KCHUNK / 32; // 4 / 2
  __shared__ float red[16 * 16 * 40];  // [wave][n][m_local pad 32->40]

  const int tid = threadIdx.x;
  const int w = tid >> 6;
  const int l = tid & 63;
  const int ln = l & 15;
  const int lg = l >> 4;
  const int n0 = (blockIdx.x & 127) * 16;
  const int mb = (blockIdx.x >> 7) * 32;  // M-half base

  f32x4 acc[2];
#pragma unroll
  for (int mt = 0; mt < 2; ++mt) acc[mt] = f32x4{0.f, 0.f, 0.f, 0.f};

  const float* grow[2];
#pragma unroll
  for (int mt = 0; mt < 2; ++mt) {
    if constexpr (GATHER) {
      const int m = mb + ln + 16 * mt;
      const int tok = X[m * SEQT + (SEQT - 1)];
      grow[mt] = emb + (size_t)tok * EMB;
    } else {
      grow[mt] = nullptr;
    }
  }

  const int kwave = w * KCHUNK + lg * 8;
  const float* Wc = W + n0 + ln;

  // hoist ALL W loads for this wave's K-chunk
  float wv[KSTEPS * 8];
#pragma unroll
  for (int j = 0; j < KSTEPS * 8; ++j)
    wv[j] = Wc[(size_t)(kwave + (j >> 3) * 32 + (j & 7)) * HID];

  // hoist ALL A fragments (split-bf16 planes)
  bf16x8 Ah[2][KSTEPS], Al[2][KSTEPS];
  if constexpr (GATHER) {
#pragma unroll
    for (int mt = 0; mt < 2; ++mt)
#pragma unroll
      for (int ks = 0; ks < KSTEPS; ++ks) {
        const float* p = grow[mt] + kwave + ks * 32;
        const f32x4 v0 = *reinterpret_cast<const f32x4*>(p);
        const f32x4 v1 = *reinterpret_cast<const f32x4*>(p + 4);
#pragma unroll
        for (int i = 0; i < 4; ++i) {
          __bf16 h_, l_;
          split2(v0[i], h_, l_);
          Ah[mt][ks][i] = h_;
          Al[mt][ks][i] = l_;
          split2(v1[i], h_, l_);
          Ah[mt][ks][4 + i] = h_;
          Al[mt][ks][4 + i] = l_;
        }
      }
  } else {
#pragma unroll
    for (int mt = 0; mt < 2; ++mt)
#pragma unroll
      for (int ks = 0; ks < KSTEPS; ++ks) {
        const size_t off = (size_t)(mb + ln + 16 * mt) * KTOT + kwave + ks * 32;
        Ah[mt][ks] = *reinterpret_cast<const bf16x8*>(hin_hi + off);
        Al[mt][ks] = *reinterpret_cast<const bf16x8*>(hin_lo + off);
      }
  }

#pragma unroll
  for (int ks = 0; ks < KSTEPS; ++ks) {
    bf16x8 bhi, blo;
#pragma unroll
    for (int i = 0; i < 8; ++i) {
      __bf16 h_, l_;
      split2(wv[ks * 8 + i], h_, l_);
      bhi[i] = h_;
      blo[i] = l_;
    }
#pragma unroll
    for (int mt = 0; mt < 2; ++mt) {
      acc[mt] = __builtin_amdgcn_mfma_f32_16x16x32_bf16(Ah[mt][ks], bhi, acc[mt], 0, 0, 0);
      acc[mt] = __builtin_amdgcn_mfma_f32_16x16x32_bf16(Al[mt][ks], bhi, acc[mt], 0, 0, 0);
      acc[mt] = __builtin_amdgcn_mfma_f32_16x16x32_bf16(Ah[mt][ks], blo, acc[mt], 0, 0, 0);
    }
  }

  // stash: red[(w*16+n)*40 + m_local]; acc[mt][j] -> m_local = mt*16+lg*4+j
  float* dst = &red[(w * 16 + ln) * 40 + lg * 4];
#pragma unroll
  for (int mt = 0; mt < 2; ++mt)
    *reinterpret_cast<f32x4*>(dst + mt * 16) = acc[mt];

  __syncthreads();

  if (tid < 512) {
    const int m = tid >> 4, n = tid & 15;  // m_local 0..31
    float s = 0.f;
#pragma unroll
    for (int ww = 0; ww < 16; ++ww) s += red[(ww * 16 + n) * 40 + m];
    s += bias[n0 + n];
    const float hval = tanhf(s);
    __bf16 h_, l_;
    split2(hval, h_, l_);
    const size_t off = (size_t)(mb + m) * HID + (n0 + n);
    hout_hi[off] = *reinterpret_cast<__hip_bfloat16*>(&h_);
    hout_lo[off] = *reinterpret_cast<__hip_bfloat16*>(&l_);
  }
}

// ---------------------------------------------------------------------------
// out_mfma v3: scratch[kq][m][n] = h[:, kq-slice] @ W_hy[kq-slice, :].
// r17 (passing, ~74us) + THE T3/T4 fix: __syncthreads() compiles to
// "s_waitcnt vmcnt(0) lgkmcnt(0); s_barrier", which DRAINED the 2-ahead
// GLOAD prefetch every step (the m97 barrier-drain stall). Replaced with
// raw s_barrier preceded only by lgkmcnt(0) (ds_write visibility) --
// prefetch loads stay in flight ACROSS barriers; the compiler still emits
// the minimal counted vmcnt(N) before DSWRITE consumes the registers
// (AITER's never-drain-to-0 discipline).
// Buffer-rotation safety unchanged: buf((ks+1)%3) was last read at
// COMPUTE(ks-2), sealed two barriers earlier; reg sets statically
// alternate (rule #20). Triple-buffered 48 KB LDS, 3 blocks/CU.
// Single-bf16 operands (final layer: no tanh amplification after).
// Grid: 1000 blocks = 4 kq x 250 nt. Plain scratch stores (r8 lesson).
// ---------------------------------------------------------------------------
__global__ __launch_bounds__(256) void out_mfma(
    const __hip_bfloat16* __restrict__ hhi, const float* __restrict__ Why,
    float* __restrict__ scratch) {
  __shared__ float lds[3 * 32 * 128];  // 3 x 16 KB W tiles

  const int tid = threadIdx.x;
  const int w = tid >> 6;
  const int l = tid & 63;
  const int ln = l & 15;
  const int lg = l >> 4;
  const int nt = blockIdx.x % 250;
  const int kq = blockIdx.x / 250;
  const int n0 = nt * 128;
  const int k0 = kq * 512;
  constexpr int NS = 16;  // k-steps of 32

  // staging geometry: thread covers rows (tid>>5)+{0,8,16,24}, cols (tid&31)*4
  const int srow = tid >> 5;
  const int scol = (tid & 31) * 4;

  f32x4 acc[4][2];
#pragma unroll
  for (int mf = 0; mf < 4; ++mf)
#pragma unroll
    for (int nf = 0; nf < 2; ++nf) acc[mf][nf] = f32x4{0.f, 0.f, 0.f, 0.f};

  f32x4 stA[4], stB[4];

#define GLOAD(ks_, st_)                                                      \
  {                                                                          \
    _Pragma("unroll") for (int i = 0; i < 4; ++i) {                          \
      st_[i] = __builtin_nontemporal_load(reinterpret_cast<const f32x4*>(    \
          Why + (size_t)(k0 + (ks_) * 32 + srow + i * 8) * VOC + n0 + scol));\
    }                                                                        \
  }

#define DSWRITE(buf_, st_)                                                   \
  {                                                                          \
    float* lb_ = lds + (buf_) * (32 * 128);                                  \
    _Pragma("unroll") for (int i = 0; i < 4; ++i) {                          \
      *reinterpret_cast<f32x4*>(lb_ + (srow + i * 8) * 128 + scol) = st_[i]; \
    }                                                                        \
  }

#define COMPUTE(buf_, ks_)                                                   \
  {                                                                          \
    const float* lb_ = lds + (buf_) * (32 * 128);                            \
    bf16x8 a_[4];                                                            \
    _Pragma("unroll") for (int mf = 0; mf < 4; ++mf) {                       \
      a_[mf] = *reinterpret_cast<const bf16x8*>(                             \
          hhi + (size_t)(mf * 16 + ln) * HID + k0 + (ks_) * 32 + lg * 8);    \
    }                                                                        \
    bf16x8 b_[2];                                                            \
    _Pragma("unroll") for (int nf = 0; nf < 2; ++nf) {                       \
      _Pragma("unroll") for (int i = 0; i < 8; ++i) {                        \
        b_[nf][i] =                                                          \
            (__bf16)lb_[(lg * 8 + i) * 128 + w * 32 + nf * 16 + ln];         \
      }                                                                      \
    }                                                                        \
    _Pragma("unroll") for (int mf = 0; mf < 4; ++mf) {                       \
      _Pragma("unroll") for (int nf = 0; nf < 2; ++nf) {                     \
        acc[mf][nf] = __builtin_amdgcn_mfma_f32_16x16x32_bf16(               \
            a_[mf], b_[nf], acc[mf][nf], 0, 0, 0);                           \
      }                                                                      \
    }                                                                        \
  }

// counted barrier: ds_writes visible, prefetch vmem loads stay in flight
#define CBARRIER()                                                           \
  {                                                                          \
    asm volatile("s_waitcnt lgkmcnt(0)" ::: "memory");                       \
    __builtin_amdgcn_s_barrier();                                            \
  }

  // prologue: step0 staged+written, step1 in flight
  GLOAD(0, stA);
  DSWRITE(0, stA);
  GLOAD(1, stB);
  CBARRIER();

#pragma unroll
  for (int ks = 0; ks < NS; ++ks) {
    // issue 2 ahead into the set consumed at iter ks-1
    if (ks + 2 < NS) {
      if ((ks & 1) == 0) GLOAD(ks + 2, stA) else GLOAD(ks + 2, stB);
    }
    // write 1 ahead from the set loaded at iter ks-1 (counted vmcnt cover)
    if (ks + 1 < NS) {
      if (((ks + 1) & 1) == 0) DSWRITE((ks + 1) % 3, stA)
      else DSWRITE((ks + 1) % 3, stB);
    }
    COMPUTE(ks % 3, ks);
    if (ks + 1 < NS) CBARRIER();
  }
#undef CBARRIER
#undef COMPUTE
#undef DSWRITE
#undef GLOAD

  // epilogue: C/D layout col=ln, row=lg*4+j (layer-kernel-verified).
  // PLAIN stores (kernel-to-kernel data through normal L2 path).
  float* sc = scratch + (size_t)kq * ((size_t)BATCH * VOC);
#pragma unroll
  for (int mf = 0; mf < 4; ++mf) {
#pragma unroll
    for (int nf = 0; nf < 2; ++nf) {
#pragma unroll
      for (int j = 0; j < 4; ++j) {
        const int row = mf * 16 + lg * 4 + j;
        const int col = n0 + w * 32 + nf * 16 + ln;
        sc[(size_t)row * VOC + col] = acc[mf][nf][j];
      }
    }
  }
}

// ---------------------------------------------------------------------------
// reduce_out: out[m][n] = sum_q scratch[q][m][n] + b_y[n].
// Grid (125, 64) x 256 thr; scratch is L2/L3-hot.
// ---------------------------------------------------------------------------
__global__ __launch_bounds__(256) void reduce_out(
    const float* __restrict__ scratch, const float* __restrict__ by,
    float* __restrict__ out) {
  const int n = blockIdx.x * 256 + threadIdx.x;
  const int m = blockIdx.y;
  float s = by[n];
#pragma unroll
  for (int q = 0; q < KSPLIT; ++q)
    s += scratch[(size_t)q * ((size_t)BATCH * VOC) + (size_t)m * VOC + n];
  __builtin_nontemporal_store(s, out + (size_t)m * VOC + n);
}

extern "C" void kernel_launch(void* const* d_in, const int* in_sizes, int n_in,
                              void* d_out, int out_size, void* d_ws,
                              size_t ws_size, hipStream_t stream) {
  const int* X = (const int*)d_in[0];
  const float* emb = (const float*)d_in[1];
  const float* W_xh = (const float*)d_in[2];
  const float* W_hh = (const float*)d_in[3];
  const float* W_hy = (const float*)d_in[4];
  const float* b_h = (const float*)d_in[5];
  const float* b_y = (const float*)d_in[6];
  float* out = (float*)d_out;

  char* ws = (char*)d_ws;
  const size_t PLANE = (size_t)BATCH * HID;  // elements
  __hip_bfloat16* hA_hi = (__hip_bfloat16*)ws;
  __hip_bfloat16* hA_lo = hA_hi + PLANE;
  __hip_bfloat16* hB_hi = hA_lo + PLANE;
  __hip_bfloat16* hB_lo = hB_hi + PLANE;
  float* scratch = (float*)(ws + 4 * PLANE * sizeof(__hip_bfloat16));
  // scratch: KSPLIT(4) x 64 x 32000 f32 = 32.8 MB

  dim3 blk(1024), grd(256);
  layer_kernel<EMB, true><<<grd, blk, 0, stream>>>(
      X, emb, nullptr, nullptr, W_xh, b_h, hA_hi, hA_lo);
  layer_kernel<HID, false><<<grd, blk, 0, stream>>>(
      nullptr, nullptr, hA_hi, hA_lo, W_hh, b_h, hB_hi, hB_lo);
  layer_kernel<HID, false><<<grd, blk, 0, stream>>>(
      nullptr, nullptr, hB_hi, hB_lo, W_hh, b_h, hA_hi, hA_lo);
  layer_kernel<HID, false><<<grd, blk, 0, stream>>>(
      nullptr, nullptr, hA_hi, hA_lo, W_hh, b_h, hB_hi, hB_lo);
  layer_kernel<HID, false><<<grd, blk, 0, stream>>>(
      nullptr, nullptr, hB_hi, hB_lo, W_hh, b_h, hA_hi, hA_lo);

  out_mfma<<<dim3(1000), dim3(256), 0, stream>>>(hA_hi, W_hy, scratch);
  reduce_out<<<dim3(125, 64), dim3(256), 0, stream>>>(scratch, b_y, out);
}

// Round 20
// 126.254 us; speedup vs baseline: 1.0031x; 1.0031x over previous
//
#include <hip/hip_runtime.h>
#include <hip/hip_bf16.h>

#define BATCH 64
#define SEQT  512
#define EMB   1024
#define HID   2048
#define VOC   32000
#define KSPLIT 4

using bf16x8 = __attribute__((ext_vector_type(8))) __bf16;
using f32x4  = __attribute__((ext_vector_type(4))) float;

__device__ __forceinline__ void split2(float x, __bf16& hi, __bf16& lo) {
  hi = (__bf16)x;
  lo = (__bf16)(x - (float)hi);
}

// ---------------------------------------------------------------------------
// Layer kernel (round-9 verbatim, passing): h_out = tanh(A @ W + bias),
// split-bf16 (3 MFMA products), 16x16x32 MFMA, 256 blocks x 16 waves,
// LDS reduce.
// ---------------------------------------------------------------------------
template <int KTOT, bool GATHER>
__global__ __launch_bounds__(1024) void layer_kernel(
    const int* __restrict__ X, const float* __restrict__ emb,
    const __hip_bfloat16* __restrict__ hin_hi,
    const __hip_bfloat16* __restrict__ hin_lo,
    const float* __restrict__ W, const float* __restrict__ bias,
    __hip_bfloat16* __restrict__ hout_hi,
    __hip_bfloat16* __restrict__ hout_lo) {
  constexpr int KCHUNK = KTOT / 16;   // 128 (HID) / 64 (EMB)
  constexpr int KSTEPS = KCHUNK / 32; // 4 / 2
  __shared__ float red[16 * 16 * 40];  // [wave][n][m_local pad 32->40]

  const int tid = threadIdx.x;
  const int w = tid >> 6;
  const int l = tid & 63;
  const int ln = l & 15;
  const int lg = l >> 4;
  const int n0 = (blockIdx.x & 127) * 16;
  const int mb = (blockIdx.x >> 7) * 32;  // M-half base

  f32x4 acc[2];
#pragma unroll
  for (int mt = 0; mt < 2; ++mt) acc[mt] = f32x4{0.f, 0.f, 0.f, 0.f};

  const float* grow[2];
#pragma unroll
  for (int mt = 0; mt < 2; ++mt) {
    if constexpr (GATHER) {
      const int m = mb + ln + 16 * mt;
      const int tok = X[m * SEQT + (SEQT - 1)];
      grow[mt] = emb + (size_t)tok * EMB;
    } else {
      grow[mt] = nullptr;
    }
  }

  const int kwave = w * KCHUNK + lg * 8;
  const float* Wc = W + n0 + ln;

  // hoist ALL W loads for this wave's K-chunk
  float wv[KSTEPS * 8];
#pragma unroll
  for (int j = 0; j < KSTEPS * 8; ++j)
    wv[j] = Wc[(size_t)(kwave + (j >> 3) * 32 + (j & 7)) * HID];

  // hoist ALL A fragments (split-bf16 planes)
  bf16x8 Ah[2][KSTEPS], Al[2][KSTEPS];
  if constexpr (GATHER) {
#pragma unroll
    for (int mt = 0; mt < 2; ++mt)
#pragma unroll
      for (int ks = 0; ks < KSTEPS; ++ks) {
        const float* p = grow[mt] + kwave + ks * 32;
        const f32x4 v0 = *reinterpret_cast<const f32x4*>(p);
        const f32x4 v1 = *reinterpret_cast<const f32x4*>(p + 4);
#pragma unroll
        for (int i = 0; i < 4; ++i) {
          __bf16 h_, l_;
          split2(v0[i], h_, l_);
          Ah[mt][ks][i] = h_;
          Al[mt][ks][i] = l_;
          split2(v1[i], h_, l_);
          Ah[mt][ks][4 + i] = h_;
          Al[mt][ks][4 + i] = l_;
        }
      }
  } else {
#pragma unroll
    for (int mt = 0; mt < 2; ++mt)
#pragma unroll
      for (int ks = 0; ks < KSTEPS; ++ks) {
        const size_t off = (size_t)(mb + ln + 16 * mt) * KTOT + kwave + ks * 32;
        Ah[mt][ks] = *reinterpret_cast<const bf16x8*>(hin_hi + off);
        Al[mt][ks] = *reinterpret_cast<const bf16x8*>(hin_lo + off);
      }
  }

#pragma unroll
  for (int ks = 0; ks < KSTEPS; ++ks) {
    bf16x8 bhi, blo;
#pragma unroll
    for (int i = 0; i < 8; ++i) {
      __bf16 h_, l_;
      split2(wv[ks * 8 + i], h_, l_);
      bhi[i] = h_;
      blo[i] = l_;
    }
#pragma unroll
    for (int mt = 0; mt < 2; ++mt) {
      acc[mt] = __builtin_amdgcn_mfma_f32_16x16x32_bf16(Ah[mt][ks], bhi, acc[mt], 0, 0, 0);
      acc[mt] = __builtin_amdgcn_mfma_f32_16x16x32_bf16(Al[mt][ks], bhi, acc[mt], 0, 0, 0);
      acc[mt] = __builtin_amdgcn_mfma_f32_16x16x32_bf16(Ah[mt][ks], blo, acc[mt], 0, 0, 0);
    }
  }

  // stash: red[(w*16+n)*40 + m_local]; acc[mt][j] -> m_local = mt*16+lg*4+j
  float* dst = &red[(w * 16 + ln) * 40 + lg * 4];
#pragma unroll
  for (int mt = 0; mt < 2; ++mt)
    *reinterpret_cast<f32x4*>(dst + mt * 16) = acc[mt];

  __syncthreads();

  if (tid < 512) {
    const int m = tid >> 4, n = tid & 15;  // m_local 0..31
    float s = 0.f;
#pragma unroll
    for (int ww = 0; ww < 16; ++ww) s += red[(ww * 16 + n) * 40 + m];
    s += bias[n0 + n];
    const float hval = tanhf(s);
    __bf16 h_, l_;
    split2(hval, h_, l_);
    const size_t off = (size_t)(mb + m) * HID + (n0 + n);
    hout_hi[off] = *reinterpret_cast<__hip_bfloat16*>(&h_);
    hout_lo[off] = *reinterpret_cast<__hip_bfloat16*>(&l_);
  }
}

// ---------------------------------------------------------------------------
// out_mfma v3: scratch[kq][m][n] = h[:, kq-slice] @ W_hy[kq-slice, :].
// r17 (passing, ~74us) + THE T3/T4 fix: __syncthreads() compiles to
// "s_waitcnt vmcnt(0) lgkmcnt(0); s_barrier", which DRAINED the 2-ahead
// GLOAD prefetch every step (the m97 barrier-drain stall). Replaced with
// raw s_barrier preceded only by lgkmcnt(0) (ds_write visibility) --
// prefetch loads stay in flight ACROSS barriers; the compiler still emits
// the minimal counted vmcnt(N) before DSWRITE consumes the registers
// (AITER's never-drain-to-0 discipline).
// Buffer-rotation safety unchanged: buf((ks+1)%3) was last read at
// COMPUTE(ks-2), sealed two barriers earlier; reg sets statically
// alternate (rule #20). Triple-buffered 48 KB LDS, 3 blocks/CU.
// Single-bf16 operands (final layer: no tanh amplification after).
// Grid: 1000 blocks = 4 kq x 250 nt. Plain scratch stores (r8 lesson).
// ---------------------------------------------------------------------------
__global__ __launch_bounds__(256) void out_mfma(
    const __hip_bfloat16* __restrict__ hhi, const float* __restrict__ Why,
    float* __restrict__ scratch) {
  __shared__ float lds[3 * 32 * 128];  // 3 x 16 KB W tiles

  const int tid = threadIdx.x;
  const int w = tid >> 6;
  const int l = tid & 63;
  const int ln = l & 15;
  const int lg = l >> 4;
  const int nt = blockIdx.x % 250;
  const int kq = blockIdx.x / 250;
  const int n0 = nt * 128;
  const int k0 = kq * 512;
  constexpr int NS = 16;  // k-steps of 32

  // staging geometry: thread covers rows (tid>>5)+{0,8,16,24}, cols (tid&31)*4
  const int srow = tid >> 5;
  const int scol = (tid & 31) * 4;

  f32x4 acc[4][2];
#pragma unroll
  for (int mf = 0; mf < 4; ++mf)
#pragma unroll
    for (int nf = 0; nf < 2; ++nf) acc[mf][nf] = f32x4{0.f, 0.f, 0.f, 0.f};

  f32x4 stA[4], stB[4];

#define GLOAD(ks_, st_)                                                      \
  {                                                                          \
    _Pragma("unroll") for (int i = 0; i < 4; ++i) {                          \
      st_[i] = __builtin_nontemporal_load(reinterpret_cast<const f32x4*>(    \
          Why + (size_t)(k0 + (ks_) * 32 + srow + i * 8) * VOC + n0 + scol));\
    }                                                                        \
  }

#define DSWRITE(buf_, st_)                                                   \
  {                                                                          \
    float* lb_ = lds + (buf_) * (32 * 128);                                  \
    _Pragma("unroll") for (int i = 0; i < 4; ++i) {                          \
      *reinterpret_cast<f32x4*>(lb_ + (srow + i * 8) * 128 + scol) = st_[i]; \
    }                                                                        \
  }

#define COMPUTE(buf_, ks_)                                                   \
  {                                                                          \
    const float* lb_ = lds + (buf_) * (32 * 128);                            \
    bf16x8 a_[4];                                                            \
    _Pragma("unroll") for (int mf = 0; mf < 4; ++mf) {                       \
      a_[mf] = *reinterpret_cast<const bf16x8*>(                             \
          hhi + (size_t)(mf * 16 + ln) * HID + k0 + (ks_) * 32 + lg * 8);    \
    }                                                                        \
    bf16x8 b_[2];                                                            \
    _Pragma("unroll") for (int nf = 0; nf < 2; ++nf) {                       \
      _Pragma("unroll") for (int i = 0; i < 8; ++i) {                        \
        b_[nf][i] =                                                          \
            (__bf16)lb_[(lg * 8 + i) * 128 + w * 32 + nf * 16 + ln];         \
      }                                                                      \
    }                                                                        \
    _Pragma("unroll") for (int mf = 0; mf < 4; ++mf) {                       \
      _Pragma("unroll") for (int nf = 0; nf < 2; ++nf) {                     \
        acc[mf][nf] = __builtin_amdgcn_mfma_f32_16x16x32_bf16(               \
            a_[mf], b_[nf], acc[mf][nf], 0, 0, 0);                           \
      }                                                                      \
    }                                                                        \
  }

// counted barrier: ds_writes visible, prefetch vmem loads stay in flight
#define CBARRIER()                                                           \
  {                                                                          \
    asm volatile("s_waitcnt lgkmcnt(0)" ::: "memory");                       \
    __builtin_amdgcn_s_barrier();                                            \
  }

  // prologue: step0 staged+written, step1 in flight
  GLOAD(0, stA);
  DSWRITE(0, stA);
  GLOAD(1, stB);
  CBARRIER();

#pragma unroll
  for (int ks = 0; ks < NS; ++ks) {
    // issue 2 ahead into the set consumed at iter ks-1
    if (ks + 2 < NS) {
      if ((ks & 1) == 0) GLOAD(ks + 2, stA) else GLOAD(ks + 2, stB);
    }
    // write 1 ahead from the set loaded at iter ks-1 (counted vmcnt cover)
    if (ks + 1 < NS) {
      if (((ks + 1) & 1) == 0) DSWRITE((ks + 1) % 3, stA)
      else DSWRITE((ks + 1) % 3, stB);
    }
    COMPUTE(ks % 3, ks);
    if (ks + 1 < NS) CBARRIER();
  }
#undef CBARRIER
#undef COMPUTE
#undef DSWRITE
#undef GLOAD

  // epilogue: C/D layout col=ln, row=lg*4+j (layer-kernel-verified).
  // PLAIN stores (kernel-to-kernel data through normal L2 path).
  float* sc = scratch + (size_t)kq * ((size_t)BATCH * VOC);
#pragma unroll
  for (int mf = 0; mf < 4; ++mf) {
#pragma unroll
    for (int nf = 0; nf < 2; ++nf) {
#pragma unroll
      for (int j = 0; j < 4; ++j) {
        const int row = mf * 16 + lg * 4 + j;
        const int col = n0 + w * 32 + nf * 16 + ln;
        sc[(size_t)row * VOC + col] = acc[mf][nf][j];
      }
    }
  }
}

// ---------------------------------------------------------------------------
// reduce_out: out[m][n] = sum_q scratch[q][m][n] + b_y[n].
// Grid (125, 64) x 256 thr; scratch is L2/L3-hot.
// ---------------------------------------------------------------------------
__global__ __launch_bounds__(256) void reduce_out(
    const float* __restrict__ scratch, const float* __restrict__ by,
    float* __restrict__ out) {
  const int n = blockIdx.x * 256 + threadIdx.x;
  const int m = blockIdx.y;
  float s = by[n];
#pragma unroll
  for (int q = 0; q < KSPLIT; ++q)
    s += scratch[(size_t)q * ((size_t)BATCH * VOC) + (size_t)m * VOC + n];
  __builtin_nontemporal_store(s, out + (size_t)m * VOC + n);
}

extern "C" void kernel_launch(void* const* d_in, const int* in_sizes, int n_in,
                              void* d_out, int out_size, void* d_ws,
                              size_t ws_size, hipStream_t stream) {
  const int* X = (const int*)d_in[0];
  const float* emb = (const float*)d_in[1];
  const float* W_xh = (const float*)d_in[2];
  const float* W_hh = (const float*)d_in[3];
  const float* W_hy = (const float*)d_in[4];
  const float* b_h = (const float*)d_in[5];
  const float* b_y = (const float*)d_in[6];
  float* out = (float*)d_out;

  char* ws = (char*)d_ws;
  const size_t PLANE = (size_t)BATCH * HID;  // elements
  __hip_bfloat16* hA_hi = (__hip_bfloat16*)ws;
  __hip_bfloat16* hA_lo = hA_hi + PLANE;
  __hip_bfloat16* hB_hi = hA_lo + PLANE;
  __hip_bfloat16* hB_lo = hB_hi + PLANE;
  float* scratch = (float*)(ws + 4 * PLANE * sizeof(__hip_bfloat16));
  // scratch: KSPLIT(4) x 64 x 32000 f32 = 32.8 MB

  dim3 blk(1024), grd(256);
  layer_kernel<EMB, true><<<grd, blk, 0, stream>>>(
      X, emb, nullptr, nullptr, W_xh, b_h, hA_hi, hA_lo);
  layer_kernel<HID, false><<<grd, blk, 0, stream>>>(
      nullptr, nullptr, hA_hi, hA_lo, W_hh, b_h, hB_hi, hB_lo);
  layer_kernel<HID, false><<<grd, blk, 0, stream>>>(
      nullptr, nullptr, hB_hi, hB_lo, W_hh, b_h, hA_hi, hA_lo);
  layer_kernel<HID, false><<<grd, blk, 0, stream>>>(
      nullptr, nullptr, hA_hi, hA_lo, W_hh, b_h, hB_hi, hB_lo);
  layer_kernel<HID, false><<<grd, blk, 0, stream>>>(
      nullptr, nullptr, hB_hi, hB_lo, W_hh, b_h, hA_hi, hA_lo);

  out_mfma<<<dim3(1000), dim3(256), 0, stream>>>(hA_hi, W_hy, scratch);
  reduce_out<<<dim3(125, 64), dim3(256), 0, stream>>>(scratch, b_y, out);
}

// Round 21
// 126.174 us; speedup vs baseline: 1.0037x; 1.0006x over previous
//
#include <hip/hip_runtime.h>
#include <hip/hip_bf16.h>

#define BATCH 64
#define SEQT  512
#define EMB   1024
#define HID   2048
#define VOC   32000
#define KSPLIT 4

using bf16x8 = __attribute__((ext_vector_type(8))) __bf16;
using f32x4  = __attribute__((ext_vector_type(4))) float;

__device__ __forceinline__ void split2(float x, __bf16& hi, __bf16& lo) {
  hi = (__bf16)x;
  lo = (__bf16)(x - (float)hi);
}

// ---------------------------------------------------------------------------
// Layer kernel (round-9 verbatim, passing): h_out = tanh(A @ W + bias),
// split-bf16 (3 MFMA products), 16x16x32 MFMA, 256 blocks x 16 waves,
// LDS reduce.
// ---------------------------------------------------------------------------
template <int KTOT, bool GATHER>
__global__ __launch_bounds__(1024) void layer_kernel(
    const int* __restrict__ X, const float* __restrict__ emb,
    const __hip_bfloat16* __restrict__ hin_hi,
    const __hip_bfloat16* __restrict__ hin_lo,
    const float* __restrict__ W, const float* __restrict__ bias,
    __hip_bfloat16* __restrict__ hout_hi,
    __hip_bfloat16* __restrict__ hout_lo) {
  constexpr int KCHUNK = KTOT / 16;   // 128 (HID) / 64 (EMB)
  constexpr int KSTEPS = KCHUNK / 32; // 4 / 2
  __shared__ float red[16 * 16 * 40];  // [wave][n][m_local pad 32->40]

  const int tid = threadIdx.x;
  const int w = tid >> 6;
  const int l = tid & 63;
  const int ln = l & 15;
  const int lg = l >> 4;
  const int n0 = (blockIdx.x & 127) * 16;
  const int mb = (blockIdx.x >> 7) * 32;  // M-half base

  f32x4 acc[2];
#pragma unroll
  for (int mt = 0; mt < 2; ++mt) acc[mt] = f32x4{0.f, 0.f, 0.f, 0.f};

  const float* grow[2];
#pragma unroll
  for (int mt = 0; mt < 2; ++mt) {
    if constexpr (GATHER) {
      const int m = mb + ln + 16 * mt;
      const int tok = X[m * SEQT + (SEQT - 1)];
      grow[mt] = emb + (size_t)tok * EMB;
    } else {
      grow[mt] = nullptr;
    }
  }

  const int kwave = w * KCHUNK + lg * 8;
  const float* Wc = W + n0 + ln;

  // hoist ALL W loads for this wave's K-chunk
  float wv[KSTEPS * 8];
#pragma unroll
  for (int j = 0; j < KSTEPS * 8; ++j)
    wv[j] = Wc[(size_t)(kwave + (j >> 3) * 32 + (j & 7)) * HID];

  // hoist ALL A fragments (split-bf16 planes)
  bf16x8 Ah[2][KSTEPS], Al[2][KSTEPS];
  if constexpr (GATHER) {
#pragma unroll
    for (int mt = 0; mt < 2; ++mt)
#pragma unroll
      for (int ks = 0; ks < KSTEPS; ++ks) {
        const float* p = grow[mt] + kwave + ks * 32;
        const f32x4 v0 = *reinterpret_cast<const f32x4*>(p);
        const f32x4 v1 = *reinterpret_cast<const f32x4*>(p + 4);
#pragma unroll
        for (int i = 0; i < 4; ++i) {
          __bf16 h_, l_;
          split2(v0[i], h_, l_);
          Ah[mt][ks][i] = h_;
          Al[mt][ks][i] = l_;
          split2(v1[i], h_, l_);
          Ah[mt][ks][4 + i] = h_;
          Al[mt][ks][4 + i] = l_;
        }
      }
  } else {
#pragma unroll
    for (int mt = 0; mt < 2; ++mt)
#pragma unroll
      for (int ks = 0; ks < KSTEPS; ++ks) {
        const size_t off = (size_t)(mb + ln + 16 * mt) * KTOT + kwave + ks * 32;
        Ah[mt][ks] = *reinterpret_cast<const bf16x8*>(hin_hi + off);
        Al[mt][ks] = *reinterpret_cast<const bf16x8*>(hin_lo + off);
      }
  }

#pragma unroll
  for (int ks = 0; ks < KSTEPS; ++ks) {
    bf16x8 bhi, blo;
#pragma unroll
    for (int i = 0; i < 8; ++i) {
      __bf16 h_, l_;
      split2(wv[ks * 8 + i], h_, l_);
      bhi[i] = h_;
      blo[i] = l_;
    }
#pragma unroll
    for (int mt = 0; mt < 2; ++mt) {
      acc[mt] = __builtin_amdgcn_mfma_f32_16x16x32_bf16(Ah[mt][ks], bhi, acc[mt], 0, 0, 0);
      acc[mt] = __builtin_amdgcn_mfma_f32_16x16x32_bf16(Al[mt][ks], bhi, acc[mt], 0, 0, 0);
      acc[mt] = __builtin_amdgcn_mfma_f32_16x16x32_bf16(Ah[mt][ks], blo, acc[mt], 0, 0, 0);
    }
  }

  // stash: red[(w*16+n)*40 + m_local]; acc[mt][j] -> m_local = mt*16+lg*4+j
  float* dst = &red[(w * 16 + ln) * 40 + lg * 4];
#pragma unroll
  for (int mt = 0; mt < 2; ++mt)
    *reinterpret_cast<f32x4*>(dst + mt * 16) = acc[mt];

  __syncthreads();

  if (tid < 512) {
    const int m = tid >> 4, n = tid & 15;  // m_local 0..31
    float s = 0.f;
#pragma unroll
    for (int ww = 0; ww < 16; ++ww) s += red[(ww * 16 + n) * 40 + m];
    s += bias[n0 + n];
    const float hval = tanhf(s);
    __bf16 h_, l_;
    split2(hval, h_, l_);
    const size_t off = (size_t)(mb + m) * HID + (n0 + n);
    hout_hi[off] = *reinterpret_cast<__hip_bfloat16*>(&h_);
    hout_lo[off] = *reinterpret_cast<__hip_bfloat16*>(&l_);
  }
}

// ---------------------------------------------------------------------------
// out_mfma v3: scratch[kq][m][n] = h[:, kq-slice] @ W_hy[kq-slice, :].
// r17 (passing, ~74us) + THE T3/T4 fix: __syncthreads() compiles to
// "s_waitcnt vmcnt(0) lgkmcnt(0); s_barrier", which DRAINED the 2-ahead
// GLOAD prefetch every step (the m97 barrier-drain stall). Replaced with
// raw s_barrier preceded only by lgkmcnt(0) (ds_write visibility) --
// prefetch loads stay in flight ACROSS barriers; the compiler still emits
// the minimal counted vmcnt(N) before DSWRITE consumes the registers
// (AITER's never-drain-to-0 discipline).
// Buffer-rotation safety unchanged: buf((ks+1)%3) was last read at
// COMPUTE(ks-2), sealed two barriers earlier; reg sets statically
// alternate (rule #20). Triple-buffered 48 KB LDS, 3 blocks/CU.
// Single-bf16 operands (final layer: no tanh amplification after).
// Grid: 1000 blocks = 4 kq x 250 nt. Plain scratch stores (r8 lesson).
// ---------------------------------------------------------------------------
__global__ __launch_bounds__(256) void out_mfma(
    const __hip_bfloat16* __restrict__ hhi, const float* __restrict__ Why,
    float* __restrict__ scratch) {
  __shared__ float lds[3 * 32 * 128];  // 3 x 16 KB W tiles

  const int tid = threadIdx.x;
  const int w = tid >> 6;
  const int l = tid & 63;
  const int ln = l & 15;
  const int lg = l >> 4;
  const int nt = blockIdx.x % 250;
  const int kq = blockIdx.x / 250;
  const int n0 = nt * 128;
  const int k0 = kq * 512;
  constexpr int NS = 16;  // k-steps of 32

  // staging geometry: thread covers rows (tid>>5)+{0,8,16,24}, cols (tid&31)*4
  const int srow = tid >> 5;
  const int scol = (tid & 31) * 4;

  f32x4 acc[4][2];
#pragma unroll
  for (int mf = 0; mf < 4; ++mf)
#pragma unroll
    for (int nf = 0; nf < 2; ++nf) acc[mf][nf] = f32x4{0.f, 0.f, 0.f, 0.f};

  f32x4 stA[4], stB[4];

#define GLOAD(ks_, st_)                                                      \
  {                                                                          \
    _Pragma("unroll") for (int i = 0; i < 4; ++i) {                          \
      st_[i] = __builtin_nontemporal_load(reinterpret_cast<const f32x4*>(    \
          Why + (size_t)(k0 + (ks_) * 32 + srow + i * 8) * VOC + n0 + scol));\
    }                                                                        \
  }

#define DSWRITE(buf_, st_)                                                   \
  {                                                                          \
    float* lb_ = lds + (buf_) * (32 * 128);                                  \
    _Pragma("unroll") for (int i = 0; i < 4; ++i) {                          \
      *reinterpret_cast<f32x4*>(lb_ + (srow + i * 8) * 128 + scol) = st_[i]; \
    }                                                                        \
  }

#define COMPUTE(buf_, ks_)                                                   \
  {                                                                          \
    const float* lb_ = lds + (buf_) * (32 * 128);                            \
    bf16x8 a_[4];                                                            \
    _Pragma("unroll") for (int mf = 0; mf < 4; ++mf) {                       \
      a_[mf] = *reinterpret_cast<const bf16x8*>(                             \
          hhi + (size_t)(mf * 16 + ln) * HID + k0 + (ks_) * 32 + lg * 8);    \
    }                                                                        \
    bf16x8 b_[2];                                                            \
    _Pragma("unroll") for (int nf = 0; nf < 2; ++nf) {                       \
      _Pragma("unroll") for (int i = 0; i < 8; ++i) {                        \
        b_[nf][i] =                                                          \
            (__bf16)lb_[(lg * 8 + i) * 128 + w * 32 + nf * 16 + ln];         \
      }                                                                      \
    }                                                                        \
    _Pragma("unroll") for (int mf = 0; mf < 4; ++mf) {                       \
      _Pragma("unroll") for (int nf = 0; nf < 2; ++nf) {                     \
        acc[mf][nf] = __builtin_amdgcn_mfma_f32_16x16x32_bf16(               \
            a_[mf], b_[nf], acc[mf][nf], 0, 0, 0);                           \
      }                                                                      \
    }                                                                        \
  }

// counted barrier: ds_writes visible, prefetch vmem loads stay in flight
#define CBARRIER()                                                           \
  {                                                                          \
    asm volatile("s_waitcnt lgkmcnt(0)" ::: "memory");                       \
    __builtin_amdgcn_s_barrier();                                            \
  }

  // prologue: step0 staged+written, step1 in flight
  GLOAD(0, stA);
  DSWRITE(0, stA);
  GLOAD(1, stB);
  CBARRIER();

#pragma unroll
  for (int ks = 0; ks < NS; ++ks) {
    // issue 2 ahead into the set consumed at iter ks-1
    if (ks + 2 < NS) {
      if ((ks & 1) == 0) GLOAD(ks + 2, stA) else GLOAD(ks + 2, stB);
    }
    // write 1 ahead from the set loaded at iter ks-1 (counted vmcnt cover)
    if (ks + 1 < NS) {
      if (((ks + 1) & 1) == 0) DSWRITE((ks + 1) % 3, stA)
      else DSWRITE((ks + 1) % 3, stB);
    }
    COMPUTE(ks % 3, ks);
    if (ks + 1 < NS) CBARRIER();
  }
#undef CBARRIER
#undef COMPUTE
#undef DSWRITE
#undef GLOAD

  // epilogue: C/D layout col=ln, row=lg*4+j (layer-kernel-verified).
  // PLAIN stores (kernel-to-kernel data through normal L2 path).
  float* sc = scratch + (size_t)kq * ((size_t)BATCH * VOC);
#pragma unroll
  for (int mf = 0; mf < 4; ++mf) {
#pragma unroll
    for (int nf = 0; nf < 2; ++nf) {
#pragma unroll
      for (int j = 0; j < 4; ++j) {
        const int row = mf * 16 + lg * 4 + j;
        const int col = n0 + w * 32 + nf * 16 + ln;
        sc[(size_t)row * VOC + col] = acc[mf][nf][j];
      }
    }
  }
}

// ---------------------------------------------------------------------------
// reduce_out: out[m][n] = sum_q scratch[q][m][n] + b_y[n].
// Grid (125, 64) x 256 thr; scratch is L2/L3-hot.
// ---------------------------------------------------------------------------
__global__ __launch_bounds__(256) void reduce_out(
    const float* __restrict__ scratch, const float* __restrict__ by,
    float* __restrict__ out) {
  const int n = blockIdx.x * 256 + threadIdx.x;
  const int m = blockIdx.y;
  float s = by[n];
#pragma unroll
  for (int q = 0; q < KSPLIT; ++q)
    s += scratch[(size_t)q * ((size_t)BATCH * VOC) + (size_t)m * VOC + n];
  __builtin_nontemporal_store(s, out + (size_t)m * VOC + n);
}

extern "C" void kernel_launch(void* const* d_in, const int* in_sizes, int n_in,
                              void* d_out, int out_size, void* d_ws,
                              size_t ws_size, hipStream_t stream) {
  const int* X = (const int*)d_in[0];
  const float* emb = (const float*)d_in[1];
  const float* W_xh = (const float*)d_in[2];
  const float* W_hh = (const float*)d_in[3];
  const float* W_hy = (const float*)d_in[4];
  const float* b_h = (const float*)d_in[5];
  const float* b_y = (const float*)d_in[6];
  float* out = (float*)d_out;

  char* ws = (char*)d_ws;
  const size_t PLANE = (size_t)BATCH * HID;  // elements
  __hip_bfloat16* hA_hi = (__hip_bfloat16*)ws;
  __hip_bfloat16* hA_lo = hA_hi + PLANE;
  __hip_bfloat16* hB_hi = hA_lo + PLANE;
  __hip_bfloat16* hB_lo = hB_hi + PLANE;
  float* scratch = (float*)(ws + 4 * PLANE * sizeof(__hip_bfloat16));
  // scratch: KSPLIT(4) x 64 x 32000 f32 = 32.8 MB

  dim3 blk(1024), grd(256);
  layer_kernel<EMB, true><<<grd, blk, 0, stream>>>(
      X, emb, nullptr, nullptr, W_xh, b_h, hA_hi, hA_lo);
  layer_kernel<HID, false><<<grd, blk, 0, stream>>>(
      nullptr, nullptr, hA_hi, hA_lo, W_hh, b_h, hB_hi, hB_lo);
  layer_kernel<HID, false><<<grd, blk, 0, stream>>>(
      nullptr, nullptr, hB_hi, hB_lo, W_hh, b_h, hA_hi, hA_lo);
  layer_kernel<HID, false><<<grd, blk, 0, stream>>>(
      nullptr, nullptr, hA_hi, hA_lo, W_hh, b_h, hB_hi, hB_lo);
  layer_kernel<HID, false><<<grd, blk, 0, stream>>>(
      nullptr, nullptr, hB_hi, hB_lo, W_hh, b_h, hA_hi, hA_lo);

  out_mfma<<<dim3(1000), dim3(256), 0, stream>>>(hA_hi, W_hy, scratch);
  reduce_out<<<dim3(125, 64), dim3(256), 0, stream>>>(scratch, b_y, out);
}